// Round 2
// baseline (350.619 us; speedup 1.0000x reference)
//
#include <hip/hip_runtime.h>
#include <math.h>

// Legendre-KAN: y[n,o] = sum_{i,d} P_d(xn[n,i]) * coeffs[o,i,d] + bias[o]
// GEMM: A[65536 x 4096] (on-the-fly scaled-Legendre basis, bf16) * B[4096 x 64] (bf16).
//
// R2: fix VGPR pressure in k_main. Bq ring 4 -> 2 slots (distance-1 B prefetch;
// B is L2-resident so ~200cyc latency is covered by one ktl body). ~143 live VGPRs
// -> fits 3 waves/SIMD cap (~170) with NO scratch spill (R1 was ~175 -> spilling).
// Ring slot = ktl&1 is c-independent (compile-time static; rule-#20 safe).
// Epilogue parallelized: wave w owns row-group f=w; other 3 waves deposit that
// group's 4 ct-fragments in LDS (3 writers x 4 groups x 4KB = 48KB exactly).

typedef __bf16 bf16x8 __attribute__((ext_vector_type(8)));
typedef float f32x4 __attribute__((ext_vector_type(4)));

__device__ __forceinline__ void gload_lds16(const float* g, void* lds) {
  // dest = wave-uniform base + lane*16 (linear); source is per-lane.
  __builtin_amdgcn_global_load_lds(
      static_cast<const unsigned int*>(static_cast<const void*>(g)),
      static_cast<unsigned int*>(lds), 16, 0, 0);
}

// ---------------- pass 1: fused B-prep (blocks < 128) + per-block min/max ----------------
// Bws[(kt*4+ct)*64 + lane][j] = coeffs[o=ct*16+(lane&15)][i=kt*4+(lane>>4)][d=j] * g[j]
__global__ __launch_bounds__(256) void k_pre(
    const float4* __restrict__ x4, int n4,
    float* __restrict__ pmn, float* __restrict__ pmx,
    const float* __restrict__ coeffs, bf16x8* __restrict__ Bws, int doprep)
{
  if (doprep && blockIdx.x < 128) {
    int t = blockIdx.x * 256 + threadIdx.x;   // [0, 32768)
    int lane = t & 63;
    int tile = t >> 6;                        // kt*4 + ct
    int ct = tile & 3;
    int kt = tile >> 2;
    int ii = kt * 4 + (lane >> 4);
    int o  = ct * 16 + (lane & 15);
    const float4* cp = (const float4*)(coeffs + ((size_t)o * 512 + ii) * 8);
    float4 c0 = cp[0], c1 = cp[1];
    // g_n: P_n = g_n * S_n;  g = {1,1,1.5,2.5,4.375,7.875,14.4375,26.8125}
    bf16x8 v;
    v[0] = (__bf16)(c0.x);
    v[1] = (__bf16)(c0.y);
    v[2] = (__bf16)(c0.z * 1.5f);
    v[3] = (__bf16)(c0.w * 2.5f);
    v[4] = (__bf16)(c1.x * 4.375f);
    v[5] = (__bf16)(c1.y * 7.875f);
    v[6] = (__bf16)(c1.z * 14.4375f);
    v[7] = (__bf16)(c1.w * 26.8125f);
    Bws[(size_t)(kt * 4 + ct) * 64 + lane] = v;
  }
  float mn = 3.4e38f, mx = -3.4e38f;
  int stride = gridDim.x * 256;
  for (int i = blockIdx.x * 256 + threadIdx.x; i < n4; i += stride) {
    float4 v = x4[i];
    mn = fminf(mn, fminf(fminf(v.x, v.y), fminf(v.z, v.w)));
    mx = fmaxf(mx, fmaxf(fmaxf(v.x, v.y), fmaxf(v.z, v.w)));
  }
  #pragma unroll
  for (int off = 32; off > 0; off >>= 1) {
    mn = fminf(mn, __shfl_down(mn, off));
    mx = fmaxf(mx, __shfl_down(mx, off));
  }
  __shared__ float smn[4], smx[4];
  int w = threadIdx.x >> 6;
  if ((threadIdx.x & 63) == 0) { smn[w] = mn; smx[w] = mx; }
  __syncthreads();
  if (threadIdx.x == 0) {
    pmn[blockIdx.x] = fminf(fminf(smn[0], smn[1]), fminf(smn[2], smn[3]));
    pmx[blockIdx.x] = fmaxf(fmaxf(smx[0], smx[1]), fmaxf(smx[2], smx[3]));
  }
}

// ---------------- pass 2: fused basis + MFMA GEMM, cooperative gload_lds staging ----------
// LDS x-buffer: 2 x [64 rows][64 cols] f32 (16 KiB each), linear, swizzled:
//   phys float4-slot(row, cf) holds logical cf ^ (row & 15).
// Stage: wave w, instr p: dest slots [(w*4+p)*64 .. +64) -> rows 16w+4p..+4, cfp = lane&15;
//   source = x[row][c*64 + (cfp ^ (row&15))*4 ..) -> 16 lanes cover one 256B row-segment
//   (permuted order; coalescer merges to 4 full 64B lines).
// Read (per kt, per f): float idx = (f*16+m)*64 + ((4w+ktl)^m)*4 + quad
//   -> bank 4*(((4w+ktl)^m)&7) + quad: exactly 2 lanes/bank = free (m136).
#define NPART 2048
__global__ __launch_bounds__(256, 3) void k_main(
    const float* __restrict__ x, const bf16x8* __restrict__ Bws,
    const float* __restrict__ bias, const float* __restrict__ pmn,
    const float* __restrict__ pmx, float* __restrict__ y)
{
  __shared__ __attribute__((aligned(16))) char smem[49152]; // 2x16K stage; 48K reduce (reuse)

  const int t    = threadIdx.x;
  const int lane = t & 63;
  const int w    = t >> 6;
  const int m    = lane & 15;
  const int quad = lane >> 4;
  const size_t blockRow = (size_t)blockIdx.x * 64;

  // per-lane global source pointers for the 4 staging instructions (chunk-invariant)
  const float* gp[4];
  #pragma unroll
  for (int p = 0; p < 4; ++p) {
    int r15 = 4 * p + quad;          // row & 15
    int row = 16 * w + r15;
    int cfl = m ^ r15;               // source float4-col = phys ^ (row&15)
    gp[p] = x + (size_t)(blockRow + row) * 512 + cfl * 4;
  }
  // issue chunk-0 stage immediately (needs no scale)
  #pragma unroll
  for (int p = 0; p < 4; ++p)
    gload_lds16(gp[p], smem + (w * 4 + p) * 1024);

  // per-wave redundant reduce of the 2048 min/max partials (overlaps the stage; no LDS)
  float mn = 3.4e38f, mx = -3.4e38f;
  #pragma unroll
  for (int j = 0; j < NPART / 64; ++j) {
    mn = fminf(mn, pmn[lane + j * 64]);
    mx = fmaxf(mx, pmx[lane + j * 64]);
  }
  #pragma unroll
  for (int o2 = 32; o2 > 0; o2 >>= 1) {
    mn = fminf(mn, __shfl_xor(mn, o2));
    mx = fmaxf(mx, __shfl_xor(mx, o2));
  }
  const float s   = 2.0f / (mx - mn);
  const float off = fmaf(-mn, s, -1.0f);   // xn = x*s + off

  // B ring: 2 slots, distance-1. slot = l&1 (ktl&1: compile-time static).
  bf16x8 Bq[2][4];
  #pragma unroll
  for (int ct = 0; ct < 4; ++ct)
    Bq[0][ct] = Bws[(size_t)((4 * w + 0) * 4 + ct) * 64 + lane];

  f32x4 acc[4][4];
  #pragma unroll
  for (int f = 0; f < 4; ++f)
    #pragma unroll
    for (int ct = 0; ct < 4; ++ct) acc[f][ct] = (f32x4){0.f, 0.f, 0.f, 0.f};

  int xbase[4], xo[4];
  #pragma unroll
  for (int f = 0; f < 4; ++f) xbase[f] = (f * 16 + m) * 64 + quad;
  #pragma unroll
  for (int k = 0; k < 4; ++k) xo[k] = ((4 * w + k) ^ m) << 2;

  // scaled-recurrence constants c_n = b_n*g_{n-2}/g_n  (S_n = xn*S_{n-1} - c_n*S_{n-2})
  const float C2 = 0.33333334f, C3 = 0.26666668f, C4 = 0.25714287f;
  const float C5 = 0.25396827f, C6 = 0.25252524f, C7 = 0.25174826f;

  __syncthreads();   // chunk-0 stage complete (vmcnt drained by syncthreads)

  for (int c = 0; c < 8; ++c) {          // 8 chunks x (4 kt/wave) = 32 kt/wave
    const float* xr = (const float*)(smem + (c & 1) * 16384);

    if (c < 7) {                         // issue next chunk's stage into other buffer
      char* lb = smem + ((c + 1) & 1) * 16384;
      #pragma unroll
      for (int p = 0; p < 4; ++p)
        gload_lds16(gp[p] + (c + 1) * 64, lb + (w * 4 + p) * 1024);
    }

    float xvv[2][4];
    #pragma unroll
    for (int f = 0; f < 4; ++f) xvv[0][f] = xr[xbase[f] + xo[0]];

    #pragma unroll
    for (int ktl = 0; ktl < 4; ++ktl) {
      const int l = c * 4 + ktl;         // local kt in [0,32)

      { // B prefetch distance 1, 2-slot ring (slot = l&1, static per ktl)
        const int lp  = (l + 1) & 31;
        const int ktg = ((lp >> 2) << 4) + 4 * w + (lp & 3);   // global kt
        #pragma unroll
        for (int ct = 0; ct < 4; ++ct)
          Bq[(ktl + 1) & 1][ct] = Bws[(size_t)(ktg * 4 + ct) * 64 + lane];
      }
      if (ktl < 3) {
        #pragma unroll
        for (int f = 0; f < 4; ++f)
          xvv[(ktl + 1) & 1][f] = xr[xbase[f] + xo[ktl + 1]];
      }

      #pragma unroll
      for (int f = 0; f < 4; ++f) {
        float xn = fmaf(xvv[ktl & 1][f], s, off);
        float s2 = fmaf(xn, xn, -C2);
        float s3 = (s2 - C3) * xn;
        float s4 = fmaf(xn, s3, -(C4 * s2));
        float s5 = fmaf(xn, s4, -(C5 * s3));
        float s6 = fmaf(xn, s5, -(C6 * s4));
        float s7 = fmaf(xn, s6, -(C7 * s5));
        bf16x8 av;
        av[0] = (__bf16)1.0f; av[1] = (__bf16)xn; av[2] = (__bf16)s2; av[3] = (__bf16)s3;
        av[4] = (__bf16)s4;   av[5] = (__bf16)s5; av[6] = (__bf16)s6; av[7] = (__bf16)s7;
        #pragma unroll
        for (int ct = 0; ct < 4; ++ct)
          acc[f][ct] = __builtin_amdgcn_mfma_f32_16x16x32_bf16(av, Bq[ktl & 1][ct], acc[f][ct], 0, 0, 0);
      }
    }
    __syncthreads();   // next-chunk stage complete AND all waves done reading this buffer
  }

  // ---- epilogue: all-wave parallel reduce. Wave w owns row-group f=w. ----
  // red layout: [group g][writer slot s(0..2)][ct][lane] f32x4
  //   idx = g*768 + s*256 + ct*64 + lane  -> 3072 f32x4 = 48 KiB (fits smem exactly)
  f32x4* red = (f32x4*)smem;
  #pragma unroll
  for (int g = 0; g < 4; ++g) {
    if (g != w) {
      int slot = w - (w > g ? 1 : 0);
      #pragma unroll
      for (int ct = 0; ct < 4; ++ct)
        red[(size_t)g * 768 + slot * 256 + ct * 64 + lane] = acc[g][ct];
    }
  }
  __syncthreads();
  {
    float bv0 = bias[m], bv1 = bias[16 + m], bv2 = bias[32 + m], bv3 = bias[48 + m];
    f32x4 vv[4];
    #pragma unroll
    for (int ct = 0; ct < 4; ++ct) {
      f32x4 v = acc[w][ct];
      v += red[(size_t)w * 768 + 0 * 256 + ct * 64 + lane];
      v += red[(size_t)w * 768 + 1 * 256 + ct * 64 + lane];
      v += red[(size_t)w * 768 + 2 * 256 + ct * 64 + lane];
      vv[ct] = v;
    }
    // C/D layout: col = m, row = quad*4 + r ; this wave stores rows [w*16, w*16+16)
    float* yp = y + (blockRow + w * 16 + quad * 4) * 64 + m;
    #pragma unroll
    for (int r = 0; r < 4; ++r) {
      float* ypr = yp + r * 64;
      ypr[0]  = vv[0][r] + bv0;
      ypr[16] = vv[1][r] + bv1;
      ypr[32] = vv[2][r] + bv2;
      ypr[48] = vv[3][r] + bv3;
    }
  }
}

// ---------------- fallback-only: final min/max -> scale/offset ----------------
__global__ __launch_bounds__(256) void k_so(
    const float* __restrict__ pmn, const float* __restrict__ pmx, int nb,
    float* __restrict__ so)
{
  float mn = 3.4e38f, mx = -3.4e38f;
  for (int i = threadIdx.x; i < nb; i += 256) {
    mn = fminf(mn, pmn[i]);
    mx = fmaxf(mx, pmx[i]);
  }
  #pragma unroll
  for (int off = 32; off > 0; off >>= 1) {
    mn = fminf(mn, __shfl_down(mn, off));
    mx = fmaxf(mx, __shfl_down(mx, off));
  }
  __shared__ float smn[4], smx[4];
  int w = threadIdx.x >> 6;
  if ((threadIdx.x & 63) == 0) { smn[w] = mn; smx[w] = mx; }
  __syncthreads();
  if (threadIdx.x == 0) {
    mn = fminf(fminf(smn[0], smn[1]), fminf(smn[2], smn[3]));
    mx = fmaxf(fmaxf(smx[0], smx[1]), fmaxf(smx[2], smx[3]));
    float r = mx - mn;
    so[0] = 2.0f / r;
    so[1] = -2.0f * mn / r - 1.0f;
  }
}

// ---------------- fallback (no workspace for Bws): direct coeff loads ----------
__global__ __launch_bounds__(256) void k_main_simple(
    const float* __restrict__ x, const float* __restrict__ coeffs,
    const float* __restrict__ bias, const float* __restrict__ so, float* __restrict__ y)
{
  const float s = so[0], off = so[1];
  const int lane = threadIdx.x & 63;
  const int w    = threadIdx.x >> 6;
  const int m    = lane & 15;
  const int quad = lane >> 4;
  const int rowA = blockIdx.x * 64 + w * 16 + m;
  const float* xp = x + (size_t)rowA * 512 + quad;

  f32x4 acc0 = {0.f,0.f,0.f,0.f}, acc1 = acc0, acc2 = acc0, acc3 = acc0;
  const float c3a = 5.f/3.f, c3b = 2.f/3.f, c6a = 11.f/6.f, c6b = 5.f/6.f, c7a = 13.f/7.f, c7b = 6.f/7.f;

  for (int kt = 0; kt < 128; ++kt) {
    float xv = xp[kt * 4];
    int i = kt * 4 + quad;
    bf16x8 b[4];
    #pragma unroll
    for (int ct = 0; ct < 4; ++ct) {
      const float* cp = coeffs + ((size_t)(ct * 16 + m) * 512 + i) * 8;
      #pragma unroll
      for (int j = 0; j < 8; ++j) b[ct][j] = (__bf16)cp[j];
    }
    float xn = fmaf(xv, s, off);
    float p2 = fmaf(1.5f * xn, xn, -0.5f);
    float p3 = fmaf(c3a * xn, p2, -(c3b * xn));
    float p4 = fmaf(1.75f * xn, p3, -(0.75f * p2));
    float p5 = fmaf(1.8f * xn, p4, -(0.8f * p3));
    float p6 = fmaf(c6a * xn, p5, -(c6b * p4));
    float p7 = fmaf(c7a * xn, p6, -(c7b * p5));
    bf16x8 a;
    a[0] = (__bf16)1.0f; a[1] = (__bf16)xn; a[2] = (__bf16)p2; a[3] = (__bf16)p3;
    a[4] = (__bf16)p4;   a[5] = (__bf16)p5; a[6] = (__bf16)p6; a[7] = (__bf16)p7;
    acc0 = __builtin_amdgcn_mfma_f32_16x16x32_bf16(a, b[0], acc0, 0, 0, 0);
    acc1 = __builtin_amdgcn_mfma_f32_16x16x32_bf16(a, b[1], acc1, 0, 0, 0);
    acc2 = __builtin_amdgcn_mfma_f32_16x16x32_bf16(a, b[2], acc2, 0, 0, 0);
    acc3 = __builtin_amdgcn_mfma_f32_16x16x32_bf16(a, b[3], acc3, 0, 0, 0);
  }
  float b0v = bias[m], b1v = bias[16+m], b2v = bias[32+m], b3v = bias[48+m];
  float* yp = y + ((size_t)(blockIdx.x * 64 + w * 16 + quad * 4)) * 64 + m;
  #pragma unroll
  for (int r = 0; r < 4; ++r) {
    yp[r*64+ 0] = acc0[r] + b0v;
    yp[r*64+16] = acc1[r] + b1v;
    yp[r*64+32] = acc2[r] + b2v;
    yp[r*64+48] = acc3[r] + b3v;
  }
}

extern "C" void kernel_launch(void* const* d_in, const int* in_sizes, int n_in,
                              void* d_out, int out_size, void* d_ws, size_t ws_size,
                              hipStream_t stream)
{
  const float* x      = (const float*)d_in[0];
  const float* coeffs = (const float*)d_in[1];
  const float* bias   = (const float*)d_in[2];
  float* y = (float*)d_out;

  long nx = (long)in_sizes[0];        // 33,554,432
  int  N  = (int)(nx / 512);          // 65536 rows
  int  n4 = (int)(nx / 4);

  float*  so  = (float*)d_ws;
  float*  pmn = (float*)d_ws + 16;
  float*  pmx = pmn + 4096;
  bf16x8* Bws = (bf16x8*)((char*)d_ws + 65536);

  bool pre = ws_size >= (size_t)(65536 + 4096 * 64 * 2 + 4096);
  k_pre<<<NPART, 256, 0, stream>>>((const float4*)x, n4, pmn, pmx, coeffs, Bws, pre ? 1 : 0);
  if (pre) {
    k_main<<<N / 64, 256, 0, stream>>>(x, Bws, bias, pmn, pmx, y);
  } else {
    k_so<<<1, 256, 0, stream>>>(pmn, pmx, NPART, so);
    k_main_simple<<<N / 64, 256, 0, stream>>>(x, coeffs, bias, so, y);
  }
}

// Round 3
// 242.472 us; speedup vs baseline: 1.4460x; 1.4460x over previous
//
#include <hip/hip_runtime.h>
#include <math.h>

// Legendre-KAN: y[n,o] = sum_{i,d} P_d(xn[n,i]) * coeffs[o,i,d] + bias[o]
// GEMM: A[65536 x 4096] (on-the-fly scaled-Legendre basis, bf16) * B[4096 x 64] (bf16).
//
// R3: fix R2's rule-#20 violation. R2 read acc[w][ct] with RUNTIME w -> whole acc
// array demoted to scratch (VGPR_Count 84, 764MB phantom writes, MfmaUtil 7.8%,
// k_main 173us). Fix: unrolled g-loop + wave-uniform (g==w) guard so every acc
// access is compile-time-static. Everything else from R2 kept (2-slot distance-1
// B ring, parallel deposit epilogue, cooperative gload_lds staging w/ XOR swizzle).

typedef __bf16 bf16x8 __attribute__((ext_vector_type(8)));
typedef float f32x4 __attribute__((ext_vector_type(4)));

__device__ __forceinline__ void gload_lds16(const float* g, void* lds) {
  // dest = wave-uniform base + lane*16 (linear); source is per-lane.
  __builtin_amdgcn_global_load_lds(
      static_cast<const unsigned int*>(static_cast<const void*>(g)),
      static_cast<unsigned int*>(lds), 16, 0, 0);
}

// ---------------- pass 1: fused B-prep (blocks < 128) + per-block min/max ----------------
// Bws[(kt*4+ct)*64 + lane][j] = coeffs[o=ct*16+(lane&15)][i=kt*4+(lane>>4)][d=j] * g[j]
__global__ __launch_bounds__(256) void k_pre(
    const float4* __restrict__ x4, int n4,
    float* __restrict__ pmn, float* __restrict__ pmx,
    const float* __restrict__ coeffs, bf16x8* __restrict__ Bws, int doprep)
{
  if (doprep && blockIdx.x < 128) {
    int t = blockIdx.x * 256 + threadIdx.x;   // [0, 32768)
    int lane = t & 63;
    int tile = t >> 6;                        // kt*4 + ct
    int ct = tile & 3;
    int kt = tile >> 2;
    int ii = kt * 4 + (lane >> 4);
    int o  = ct * 16 + (lane & 15);
    const float4* cp = (const float4*)(coeffs + ((size_t)o * 512 + ii) * 8);
    float4 c0 = cp[0], c1 = cp[1];
    // g_n: P_n = g_n * S_n;  g = {1,1,1.5,2.5,4.375,7.875,14.4375,26.8125}
    bf16x8 v;
    v[0] = (__bf16)(c0.x);
    v[1] = (__bf16)(c0.y);
    v[2] = (__bf16)(c0.z * 1.5f);
    v[3] = (__bf16)(c0.w * 2.5f);
    v[4] = (__bf16)(c1.x * 4.375f);
    v[5] = (__bf16)(c1.y * 7.875f);
    v[6] = (__bf16)(c1.z * 14.4375f);
    v[7] = (__bf16)(c1.w * 26.8125f);
    Bws[(size_t)(kt * 4 + ct) * 64 + lane] = v;
  }
  float mn = 3.4e38f, mx = -3.4e38f;
  int stride = gridDim.x * 256;
  for (int i = blockIdx.x * 256 + threadIdx.x; i < n4; i += stride) {
    float4 v = x4[i];
    mn = fminf(mn, fminf(fminf(v.x, v.y), fminf(v.z, v.w)));
    mx = fmaxf(mx, fmaxf(fmaxf(v.x, v.y), fmaxf(v.z, v.w)));
  }
  #pragma unroll
  for (int off = 32; off > 0; off >>= 1) {
    mn = fminf(mn, __shfl_down(mn, off));
    mx = fmaxf(mx, __shfl_down(mx, off));
  }
  __shared__ float smn[4], smx[4];
  int w = threadIdx.x >> 6;
  if ((threadIdx.x & 63) == 0) { smn[w] = mn; smx[w] = mx; }
  __syncthreads();
  if (threadIdx.x == 0) {
    pmn[blockIdx.x] = fminf(fminf(smn[0], smn[1]), fminf(smn[2], smn[3]));
    pmx[blockIdx.x] = fmaxf(fmaxf(smx[0], smx[1]), fmaxf(smx[2], smx[3]));
  }
}

// ---------------- pass 2: fused basis + MFMA GEMM, cooperative gload_lds staging ----------
// LDS x-buffer: 2 x [64 rows][64 cols] f32 (16 KiB each), linear, swizzled:
//   phys float4-slot(row, cf) holds logical cf ^ (row & 15).
// Stage: wave w, instr p: dest slots [(w*4+p)*64 .. +64) -> rows 16w+4p..+4, cfp = lane&15;
//   source = x[row][c*64 + (cfp ^ (row&15))*4 ..) -> 16 lanes cover one 256B row-segment
//   (permuted order; coalescer merges to 4 full 64B lines).
// Read (per kt, per f): float idx = (f*16+m)*64 + ((4w+ktl)^m)*4 + quad
//   -> bank 4*(((4w+ktl)^m)&7) + quad: exactly 2 lanes/bank = free (m136).
#define NPART 2048
__global__ __launch_bounds__(256, 3) void k_main(
    const float* __restrict__ x, const bf16x8* __restrict__ Bws,
    const float* __restrict__ bias, const float* __restrict__ pmn,
    const float* __restrict__ pmx, float* __restrict__ y)
{
  __shared__ __attribute__((aligned(16))) char smem[49152]; // 2x16K stage; 48K reduce (reuse)

  const int t    = threadIdx.x;
  const int lane = t & 63;
  const int w    = t >> 6;
  const int m    = lane & 15;
  const int quad = lane >> 4;
  const size_t blockRow = (size_t)blockIdx.x * 64;

  // per-lane global source pointers for the 4 staging instructions (chunk-invariant)
  const float* gp[4];
  #pragma unroll
  for (int p = 0; p < 4; ++p) {
    int r15 = 4 * p + quad;          // row & 15
    int row = 16 * w + r15;
    int cfl = m ^ r15;               // source float4-col = phys ^ (row&15)
    gp[p] = x + (size_t)(blockRow + row) * 512 + cfl * 4;
  }
  // issue chunk-0 stage immediately (needs no scale)
  #pragma unroll
  for (int p = 0; p < 4; ++p)
    gload_lds16(gp[p], smem + (w * 4 + p) * 1024);

  // per-wave redundant reduce of the 2048 min/max partials (overlaps the stage; no LDS)
  float mn = 3.4e38f, mx = -3.4e38f;
  #pragma unroll
  for (int j = 0; j < NPART / 64; ++j) {
    mn = fminf(mn, pmn[lane + j * 64]);
    mx = fmaxf(mx, pmx[lane + j * 64]);
  }
  #pragma unroll
  for (int o2 = 32; o2 > 0; o2 >>= 1) {
    mn = fminf(mn, __shfl_xor(mn, o2));
    mx = fmaxf(mx, __shfl_xor(mx, o2));
  }
  const float s   = 2.0f / (mx - mn);
  const float off = fmaf(-mn, s, -1.0f);   // xn = x*s + off

  // B ring: 2 slots, distance-1. slot = l&1 (ktl&1: compile-time static).
  bf16x8 Bq[2][4];
  #pragma unroll
  for (int ct = 0; ct < 4; ++ct)
    Bq[0][ct] = Bws[(size_t)((4 * w + 0) * 4 + ct) * 64 + lane];

  f32x4 acc[4][4];
  #pragma unroll
  for (int f = 0; f < 4; ++f)
    #pragma unroll
    for (int ct = 0; ct < 4; ++ct) acc[f][ct] = (f32x4){0.f, 0.f, 0.f, 0.f};

  int xbase[4], xo[4];
  #pragma unroll
  for (int f = 0; f < 4; ++f) xbase[f] = (f * 16 + m) * 64 + quad;
  #pragma unroll
  for (int k = 0; k < 4; ++k) xo[k] = ((4 * w + k) ^ m) << 2;

  // scaled-recurrence constants c_n = b_n*g_{n-2}/g_n  (S_n = xn*S_{n-1} - c_n*S_{n-2})
  const float C2 = 0.33333334f, C3 = 0.26666668f, C4 = 0.25714287f;
  const float C5 = 0.25396827f, C6 = 0.25252524f, C7 = 0.25174826f;

  __syncthreads();   // chunk-0 stage complete (vmcnt drained by syncthreads)

  for (int c = 0; c < 8; ++c) {          // 8 chunks x (4 kt/wave) = 32 kt/wave
    const float* xr = (const float*)(smem + (c & 1) * 16384);

    if (c < 7) {                         // issue next chunk's stage into other buffer
      char* lb = smem + ((c + 1) & 1) * 16384;
      #pragma unroll
      for (int p = 0; p < 4; ++p)
        gload_lds16(gp[p] + (c + 1) * 64, lb + (w * 4 + p) * 1024);
    }

    float xvv[2][4];
    #pragma unroll
    for (int f = 0; f < 4; ++f) xvv[0][f] = xr[xbase[f] + xo[0]];

    #pragma unroll
    for (int ktl = 0; ktl < 4; ++ktl) {
      const int l = c * 4 + ktl;         // local kt in [0,32)

      { // B prefetch distance 1, 2-slot ring (slot = l&1, static per ktl)
        const int lp  = (l + 1) & 31;
        const int ktg = ((lp >> 2) << 4) + 4 * w + (lp & 3);   // global kt
        #pragma unroll
        for (int ct = 0; ct < 4; ++ct)
          Bq[(ktl + 1) & 1][ct] = Bws[(size_t)(ktg * 4 + ct) * 64 + lane];
      }
      if (ktl < 3) {
        #pragma unroll
        for (int f = 0; f < 4; ++f)
          xvv[(ktl + 1) & 1][f] = xr[xbase[f] + xo[ktl + 1]];
      }

      #pragma unroll
      for (int f = 0; f < 4; ++f) {
        float xn = fmaf(xvv[ktl & 1][f], s, off);
        float s2 = fmaf(xn, xn, -C2);
        float s3 = (s2 - C3) * xn;
        float s4 = fmaf(xn, s3, -(C4 * s2));
        float s5 = fmaf(xn, s4, -(C5 * s3));
        float s6 = fmaf(xn, s5, -(C6 * s4));
        float s7 = fmaf(xn, s6, -(C7 * s5));
        bf16x8 av;
        av[0] = (__bf16)1.0f; av[1] = (__bf16)xn; av[2] = (__bf16)s2; av[3] = (__bf16)s3;
        av[4] = (__bf16)s4;   av[5] = (__bf16)s5; av[6] = (__bf16)s6; av[7] = (__bf16)s7;
        #pragma unroll
        for (int ct = 0; ct < 4; ++ct)
          acc[f][ct] = __builtin_amdgcn_mfma_f32_16x16x32_bf16(av, Bq[ktl & 1][ct], acc[f][ct], 0, 0, 0);
      }
    }
    __syncthreads();   // next-chunk stage complete AND all waves done reading this buffer
  }

  // ---- epilogue: all-wave parallel reduce, ALL acc indices compile-time-static ----
  // red layout: [group g][writer slot s(0..2)][ct][lane] f32x4
  //   idx = g*768 + s*256 + ct*64 + lane  -> 3072 f32x4 = 48 KiB (fits smem exactly)
  f32x4* red = (f32x4*)smem;
  #pragma unroll
  for (int g = 0; g < 4; ++g) {
    if (g != w) {                        // wave-uniform branch; g is unroll-static
      int slot = w - (w > g ? 1 : 0);
      #pragma unroll
      for (int ct = 0; ct < 4; ++ct)
        red[(size_t)g * 768 + slot * 256 + ct * 64 + lane] = acc[g][ct];
    }
  }
  __syncthreads();
  {
    float bv0 = bias[m], bv1 = bias[16 + m], bv2 = bias[32 + m], bv3 = bias[48 + m];
    #pragma unroll
    for (int g = 0; g < 4; ++g) {
      if (g == w) {                      // wave-uniform; acc[g][ct] static (rule #20 safe)
        f32x4 vv[4];
        #pragma unroll
        for (int ct = 0; ct < 4; ++ct) {
          f32x4 v = acc[g][ct];
          v += red[(size_t)g * 768 + 0 * 256 + ct * 64 + lane];
          v += red[(size_t)g * 768 + 1 * 256 + ct * 64 + lane];
          v += red[(size_t)g * 768 + 2 * 256 + ct * 64 + lane];
          vv[ct] = v;
        }
        // C/D layout: col = m, row = quad*4 + r ; this wave stores rows [g*16, g*16+16)
        float* yp = y + (blockRow + g * 16 + quad * 4) * 64 + m;
        #pragma unroll
        for (int r = 0; r < 4; ++r) {
          float* ypr = yp + r * 64;
          ypr[0]  = vv[0][r] + bv0;
          ypr[16] = vv[1][r] + bv1;
          ypr[32] = vv[2][r] + bv2;
          ypr[48] = vv[3][r] + bv3;
        }
      }
    }
  }
}

// ---------------- fallback-only: final min/max -> scale/offset ----------------
__global__ __launch_bounds__(256) void k_so(
    const float* __restrict__ pmn, const float* __restrict__ pmx, int nb,
    float* __restrict__ so)
{
  float mn = 3.4e38f, mx = -3.4e38f;
  for (int i = threadIdx.x; i < nb; i += 256) {
    mn = fminf(mn, pmn[i]);
    mx = fmaxf(mx, pmx[i]);
  }
  #pragma unroll
  for (int off = 32; off > 0; off >>= 1) {
    mn = fminf(mn, __shfl_down(mn, off));
    mx = fmaxf(mx, __shfl_down(mx, off));
  }
  __shared__ float smn[4], smx[4];
  int w = threadIdx.x >> 6;
  if ((threadIdx.x & 63) == 0) { smn[w] = mn; smx[w] = mx; }
  __syncthreads();
  if (threadIdx.x == 0) {
    mn = fminf(fminf(smn[0], smn[1]), fminf(smn[2], smn[3]));
    mx = fmaxf(fmaxf(smx[0], smx[1]), fmaxf(smx[2], smx[3]));
    float r = mx - mn;
    so[0] = 2.0f / r;
    so[1] = -2.0f * mn / r - 1.0f;
  }
}

// ---------------- fallback (no workspace for Bws): direct coeff loads ----------
__global__ __launch_bounds__(256) void k_main_simple(
    const float* __restrict__ x, const float* __restrict__ coeffs,
    const float* __restrict__ bias, const float* __restrict__ so, float* __restrict__ y)
{
  const float s = so[0], off = so[1];
  const int lane = threadIdx.x & 63;
  const int w    = threadIdx.x >> 6;
  const int m    = lane & 15;
  const int quad = lane >> 4;
  const int rowA = blockIdx.x * 64 + w * 16 + m;
  const float* xp = x + (size_t)rowA * 512 + quad;

  f32x4 acc0 = {0.f,0.f,0.f,0.f}, acc1 = acc0, acc2 = acc0, acc3 = acc0;
  const float c3a = 5.f/3.f, c3b = 2.f/3.f, c6a = 11.f/6.f, c6b = 5.f/6.f, c7a = 13.f/7.f, c7b = 6.f/7.f;

  for (int kt = 0; kt < 128; ++kt) {
    float xv = xp[kt * 4];
    int i = kt * 4 + quad;
    bf16x8 b[4];
    #pragma unroll
    for (int ct = 0; ct < 4; ++ct) {
      const float* cp = coeffs + ((size_t)(ct * 16 + m) * 512 + i) * 8;
      #pragma unroll
      for (int j = 0; j < 8; ++j) b[ct][j] = (__bf16)cp[j];
    }
    float xn = fmaf(xv, s, off);
    float p2 = fmaf(1.5f * xn, xn, -0.5f);
    float p3 = fmaf(c3a * xn, p2, -(c3b * xn));
    float p4 = fmaf(1.75f * xn, p3, -(0.75f * p2));
    float p5 = fmaf(1.8f * xn, p4, -(0.8f * p3));
    float p6 = fmaf(c6a * xn, p5, -(c6b * p4));
    float p7 = fmaf(c7a * xn, p6, -(c7b * p5));
    bf16x8 a;
    a[0] = (__bf16)1.0f; a[1] = (__bf16)xn; a[2] = (__bf16)p2; a[3] = (__bf16)p3;
    a[4] = (__bf16)p4;   a[5] = (__bf16)p5; a[6] = (__bf16)p6; a[7] = (__bf16)p7;
    acc0 = __builtin_amdgcn_mfma_f32_16x16x32_bf16(a, b[0], acc0, 0, 0, 0);
    acc1 = __builtin_amdgcn_mfma_f32_16x16x32_bf16(a, b[1], acc1, 0, 0, 0);
    acc2 = __builtin_amdgcn_mfma_f32_16x16x32_bf16(a, b[2], acc2, 0, 0, 0);
    acc3 = __builtin_amdgcn_mfma_f32_16x16x32_bf16(a, b[3], acc3, 0, 0, 0);
  }
  float b0v = bias[m], b1v = bias[16+m], b2v = bias[32+m], b3v = bias[48+m];
  float* yp = y + ((size_t)(blockIdx.x * 64 + w * 16 + quad * 4)) * 64 + m;
  #pragma unroll
  for (int r = 0; r < 4; ++r) {
    yp[r*64+ 0] = acc0[r] + b0v;
    yp[r*64+16] = acc1[r] + b1v;
    yp[r*64+32] = acc2[r] + b2v;
    yp[r*64+48] = acc3[r] + b3v;
  }
}

extern "C" void kernel_launch(void* const* d_in, const int* in_sizes, int n_in,
                              void* d_out, int out_size, void* d_ws, size_t ws_size,
                              hipStream_t stream)
{
  const float* x      = (const float*)d_in[0];
  const float* coeffs = (const float*)d_in[1];
  const float* bias   = (const float*)d_in[2];
  float* y = (float*)d_out;

  long nx = (long)in_sizes[0];        // 33,554,432
  int  N  = (int)(nx / 512);          // 65536 rows
  int  n4 = (int)(nx / 4);

  float*  so  = (float*)d_ws;
  float*  pmn = (float*)d_ws + 16;
  float*  pmx = pmn + 4096;
  bf16x8* Bws = (bf16x8*)((char*)d_ws + 65536);

  bool pre = ws_size >= (size_t)(65536 + 4096 * 64 * 2 + 4096);
  k_pre<<<NPART, 256, 0, stream>>>((const float4*)x, n4, pmn, pmx, coeffs, Bws, pre ? 1 : 0);
  if (pre) {
    k_main<<<N / 64, 256, 0, stream>>>(x, Bws, bias, pmn, pmx, y);
  } else {
    k_so<<<1, 256, 0, stream>>>(pmn, pmx, NPART, so);
    k_main_simple<<<N / 64, 256, 0, stream>>>(x, coeffs, bias, so, y);
  }
}

// Round 4
// 238.655 us; speedup vs baseline: 1.4691x; 1.0160x over previous
//
#include <hip/hip_runtime.h>
#include <math.h>

// Legendre-KAN: y[n,o] = sum_{i,d} P_d(xn[n,i]) * coeffs[o,i,d] + bias[o]
// GEMM: A[65536 x 4096] (on-the-fly scaled-Legendre basis, bf16) * B[4096 x 64] (bf16).
//
// R4: 128-row blocks (was 64). Rationale: k_main (~65us) is stall-bound, not
// pipe-bound. (1) B fragments had ZERO intra-wave reuse -> 512 MB L2 re-stream;
// 8 f-rows/wave amortizes each B load over 2x rows (256 MB). (2) chunk compute
// was ~600cyc < 900cyc gload_lds latency -> every barrier stalled on vmcnt(0);
// doubled per-chunk compute (~1100cyc) hides staging fully. (3) barriers per row
// halve. Occupancy 3->2 blocks/CU (VGPR ~224 @ launch_bounds(256,2), LDS 64KB).
// Grid 512 = exactly 2 blocks/CU. Epilogue: 2 rounds of 48KB LDS reduce,
// all acc indices unroll-static (rule #20).

typedef __bf16 bf16x8 __attribute__((ext_vector_type(8)));
typedef float f32x4 __attribute__((ext_vector_type(4)));

__device__ __forceinline__ void gload_lds16(const float* g, void* lds) {
  // dest = wave-uniform base + lane*16 (linear); source is per-lane.
  __builtin_amdgcn_global_load_lds(
      static_cast<const unsigned int*>(static_cast<const void*>(g)),
      static_cast<unsigned int*>(lds), 16, 0, 0);
}

// ---------------- pass 1: fused B-prep (blocks < 128) + per-block min/max ----------------
// Bws[(kt*4+ct)*64 + lane][j] = coeffs[o=ct*16+(lane&15)][i=kt*4+(lane>>4)][d=j] * g[j]
__global__ __launch_bounds__(256) void k_pre(
    const float4* __restrict__ x4, int n4,
    float* __restrict__ pmn, float* __restrict__ pmx,
    const float* __restrict__ coeffs, bf16x8* __restrict__ Bws, int doprep)
{
  if (doprep && blockIdx.x < 128) {
    int t = blockIdx.x * 256 + threadIdx.x;   // [0, 32768)
    int lane = t & 63;
    int tile = t >> 6;                        // kt*4 + ct
    int ct = tile & 3;
    int kt = tile >> 2;
    int ii = kt * 4 + (lane >> 4);
    int o  = ct * 16 + (lane & 15);
    const float4* cp = (const float4*)(coeffs + ((size_t)o * 512 + ii) * 8);
    float4 c0 = cp[0], c1 = cp[1];
    // g_n: P_n = g_n * S_n;  g = {1,1,1.5,2.5,4.375,7.875,14.4375,26.8125}
    bf16x8 v;
    v[0] = (__bf16)(c0.x);
    v[1] = (__bf16)(c0.y);
    v[2] = (__bf16)(c0.z * 1.5f);
    v[3] = (__bf16)(c0.w * 2.5f);
    v[4] = (__bf16)(c1.x * 4.375f);
    v[5] = (__bf16)(c1.y * 7.875f);
    v[6] = (__bf16)(c1.z * 14.4375f);
    v[7] = (__bf16)(c1.w * 26.8125f);
    Bws[(size_t)(kt * 4 + ct) * 64 + lane] = v;
  }
  float mn = 3.4e38f, mx = -3.4e38f;
  int stride = gridDim.x * 256;
  for (int i = blockIdx.x * 256 + threadIdx.x; i < n4; i += stride) {
    float4 v = x4[i];
    mn = fminf(mn, fminf(fminf(v.x, v.y), fminf(v.z, v.w)));
    mx = fmaxf(mx, fmaxf(fmaxf(v.x, v.y), fmaxf(v.z, v.w)));
  }
  #pragma unroll
  for (int off = 32; off > 0; off >>= 1) {
    mn = fminf(mn, __shfl_down(mn, off));
    mx = fmaxf(mx, __shfl_down(mx, off));
  }
  __shared__ float smn[4], smx[4];
  int w = threadIdx.x >> 6;
  if ((threadIdx.x & 63) == 0) { smn[w] = mn; smx[w] = mx; }
  __syncthreads();
  if (threadIdx.x == 0) {
    pmn[blockIdx.x] = fminf(fminf(smn[0], smn[1]), fminf(smn[2], smn[3]));
    pmx[blockIdx.x] = fmaxf(fmaxf(smx[0], smx[1]), fmaxf(smx[2], smx[3]));
  }
}

// ---------------- pass 2: fused basis + MFMA GEMM, 128-row tile ----------
// LDS x-buffer: 2 x [128 rows][64 cols] f32 (32 KiB each), linear, swizzled:
//   phys float4-slot(row, cf) holds logical cf ^ (row & 15).
// Stage: wave w, instr p(0..7): rows 32w+4p..+3 (quad), cfp = lane&15;
//   source = x[row][c*64 + ((cfp ^ (row&15))*4 ..)] -> 16 lanes cover one 256B
//   row-segment (permuted; coalescer merges to 4 full 64B lines).
// Read (per kt, per f 0..7): float idx = (f*16+m)*64 + ((4w+ktl)^m)*4 + quad
//   -> bank 4*(((4w+ktl)^m)&7) + quad: exactly 2 lanes/bank = free (m136).
#define NPART 2048
__global__ __launch_bounds__(256, 2) void k_main(
    const float* __restrict__ x, const bf16x8* __restrict__ Bws,
    const float* __restrict__ bias, const float* __restrict__ pmn,
    const float* __restrict__ pmx, float* __restrict__ y)
{
  __shared__ __attribute__((aligned(16))) char smem[65536]; // 2x32K stage; 48K reduce (reuse)

  const int t    = threadIdx.x;
  const int lane = t & 63;
  const int w    = t >> 6;
  const int m    = lane & 15;
  const int quad = lane >> 4;
  const size_t blockRow = (size_t)blockIdx.x * 128;

  // per-lane global source pointers for the 8 staging instructions (chunk-invariant)
  const float* gp[8];
  #pragma unroll
  for (int p = 0; p < 8; ++p) {
    int r15 = (4 * p + quad) & 15;   // row & 15
    int row = 32 * w + 4 * p + quad;
    int cfl = m ^ r15;               // source float4-col = phys ^ (row&15)
    gp[p] = x + (size_t)(blockRow + row) * 512 + cfl * 4;
  }
  // issue chunk-0 stage immediately (needs no scale)
  #pragma unroll
  for (int p = 0; p < 8; ++p)
    gload_lds16(gp[p], smem + (w * 8 + p) * 1024);

  // per-wave redundant reduce of the 2048 min/max partials (overlaps the stage; no LDS)
  float mn = 3.4e38f, mx = -3.4e38f;
  #pragma unroll
  for (int j = 0; j < NPART / 64; ++j) {
    mn = fminf(mn, pmn[lane + j * 64]);
    mx = fmaxf(mx, pmx[lane + j * 64]);
  }
  #pragma unroll
  for (int o2 = 32; o2 > 0; o2 >>= 1) {
    mn = fminf(mn, __shfl_xor(mn, o2));
    mx = fmaxf(mx, __shfl_xor(mx, o2));
  }
  const float s   = 2.0f / (mx - mn);
  const float off = fmaf(-mn, s, -1.0f);   // xn = x*s + off

  // B ring: 2 slots, distance-1. slot = l&1 (ktl&1: compile-time static).
  bf16x8 Bq[2][4];
  #pragma unroll
  for (int ct = 0; ct < 4; ++ct)
    Bq[0][ct] = Bws[(size_t)((4 * w + 0) * 4 + ct) * 64 + lane];

  f32x4 acc[8][4];
  #pragma unroll
  for (int f = 0; f < 8; ++f)
    #pragma unroll
    for (int ct = 0; ct < 4; ++ct) acc[f][ct] = (f32x4){0.f, 0.f, 0.f, 0.f};

  int xbase[8], xo[4];
  #pragma unroll
  for (int f = 0; f < 8; ++f) xbase[f] = (f * 16 + m) * 64 + quad;
  #pragma unroll
  for (int k = 0; k < 4; ++k) xo[k] = ((4 * w + k) ^ m) << 2;

  // scaled-recurrence constants c_n = b_n*g_{n-2}/g_n  (S_n = xn*S_{n-1} - c_n*S_{n-2})
  const float C2 = 0.33333334f, C3 = 0.26666668f, C4 = 0.25714287f;
  const float C5 = 0.25396827f, C6 = 0.25252524f, C7 = 0.25174826f;

  __syncthreads();   // chunk-0 stage complete (vmcnt drained by syncthreads)

  for (int c = 0; c < 8; ++c) {          // 8 chunks x (4 kt/wave) = 32 kt/wave
    const float* xr = (const float*)(smem + (c & 1) * 32768);

    if (c < 7) {                         // issue next chunk's stage into other buffer
      char* lb = smem + ((c + 1) & 1) * 32768;
      #pragma unroll
      for (int p = 0; p < 8; ++p)
        gload_lds16(gp[p] + (c + 1) * 64, lb + (w * 8 + p) * 1024);
    }

    float xvv[2][8];
    #pragma unroll
    for (int f = 0; f < 8; ++f) xvv[0][f] = xr[xbase[f] + xo[0]];

    #pragma unroll
    for (int ktl = 0; ktl < 4; ++ktl) {
      const int l = c * 4 + ktl;         // local kt in [0,32)

      { // B prefetch distance 1, 2-slot ring (slot = l&1, static per ktl)
        const int lp  = (l + 1) & 31;
        const int ktg = ((lp >> 2) << 4) + 4 * w + (lp & 3);   // global kt
        #pragma unroll
        for (int ct = 0; ct < 4; ++ct)
          Bq[(ktl + 1) & 1][ct] = Bws[(size_t)(ktg * 4 + ct) * 64 + lane];
      }
      if (ktl < 3) {
        #pragma unroll
        for (int f = 0; f < 8; ++f)
          xvv[(ktl + 1) & 1][f] = xr[xbase[f] + xo[ktl + 1]];
      }

      #pragma unroll
      for (int f = 0; f < 8; ++f) {
        float xn = fmaf(xvv[ktl & 1][f], s, off);
        float s2 = fmaf(xn, xn, -C2);
        float s3 = (s2 - C3) * xn;
        float s4 = fmaf(xn, s3, -(C4 * s2));
        float s5 = fmaf(xn, s4, -(C5 * s3));
        float s6 = fmaf(xn, s5, -(C6 * s4));
        float s7 = fmaf(xn, s6, -(C7 * s5));
        bf16x8 av;
        av[0] = (__bf16)1.0f; av[1] = (__bf16)xn; av[2] = (__bf16)s2; av[3] = (__bf16)s3;
        av[4] = (__bf16)s4;   av[5] = (__bf16)s5; av[6] = (__bf16)s6; av[7] = (__bf16)s7;
        #pragma unroll
        for (int ct = 0; ct < 4; ++ct)
          acc[f][ct] = __builtin_amdgcn_mfma_f32_16x16x32_bf16(av, Bq[ktl & 1][ct], acc[f][ct], 0, 0, 0);
      }
    }
    __syncthreads();   // next-chunk stage complete AND all waves done reading this buffer
  }

  // ---- epilogue: 2 rounds x all-wave parallel reduce (48 KiB), acc static ----
  // red layout per round: [g2][slot 0..2][ct][lane] f32x4 -> 3072 f32x4 = 48 KiB
  f32x4* red = (f32x4*)smem;
  float bv0 = bias[m], bv1 = bias[16 + m], bv2 = bias[32 + m], bv3 = bias[48 + m];
  #pragma unroll
  for (int r = 0; r < 2; ++r) {
    if (r == 1) __syncthreads();         // round-0 reads done before overwriting red
    #pragma unroll
    for (int g2 = 0; g2 < 4; ++g2) {
      if (g2 != w) {                     // wave-uniform; indices unroll-static
        int slot = w - (w > g2 ? 1 : 0);
        #pragma unroll
        for (int ct = 0; ct < 4; ++ct)
          red[(size_t)g2 * 768 + slot * 256 + ct * 64 + lane] = acc[r * 4 + g2][ct];
      }
    }
    __syncthreads();
    #pragma unroll
    for (int g2 = 0; g2 < 4; ++g2) {
      if (g2 == w) {                     // wave-uniform; acc[r*4+g2] static (rule #20)
        f32x4 vv[4];
        #pragma unroll
        for (int ct = 0; ct < 4; ++ct) {
          f32x4 v = acc[r * 4 + g2][ct];
          v += red[(size_t)g2 * 768 + 0 * 256 + ct * 64 + lane];
          v += red[(size_t)g2 * 768 + 1 * 256 + ct * 64 + lane];
          v += red[(size_t)g2 * 768 + 2 * 256 + ct * 64 + lane];
          vv[ct] = v;
        }
        // C/D layout: col = m, row = quad*4 + rr ; rows [(r*4+g2)*16, +16)
        float* yp = y + (blockRow + (r * 4 + g2) * 16 + quad * 4) * 64 + m;
        #pragma unroll
        for (int rr = 0; rr < 4; ++rr) {
          float* ypr = yp + rr * 64;
          ypr[0]  = vv[0][rr] + bv0;
          ypr[16] = vv[1][rr] + bv1;
          ypr[32] = vv[2][rr] + bv2;
          ypr[48] = vv[3][rr] + bv3;
        }
      }
    }
  }
}

// ---------------- fallback-only: final min/max -> scale/offset ----------------
__global__ __launch_bounds__(256) void k_so(
    const float* __restrict__ pmn, const float* __restrict__ pmx, int nb,
    float* __restrict__ so)
{
  float mn = 3.4e38f, mx = -3.4e38f;
  for (int i = threadIdx.x; i < nb; i += 256) {
    mn = fminf(mn, pmn[i]);
    mx = fmaxf(mx, pmx[i]);
  }
  #pragma unroll
  for (int off = 32; off > 0; off >>= 1) {
    mn = fminf(mn, __shfl_down(mn, off));
    mx = fmaxf(mx, __shfl_down(mx, off));
  }
  __shared__ float smn[4], smx[4];
  int w = threadIdx.x >> 6;
  if ((threadIdx.x & 63) == 0) { smn[w] = mn; smx[w] = mx; }
  __syncthreads();
  if (threadIdx.x == 0) {
    mn = fminf(fminf(smn[0], smn[1]), fminf(smn[2], smn[3]));
    mx = fmaxf(fmaxf(smx[0], smx[1]), fmaxf(smx[2], smx[3]));
    float r = mx - mn;
    so[0] = 2.0f / r;
    so[1] = -2.0f * mn / r - 1.0f;
  }
}

// ---------------- fallback (no workspace for Bws): direct coeff loads ----------
__global__ __launch_bounds__(256) void k_main_simple(
    const float* __restrict__ x, const float* __restrict__ coeffs,
    const float* __restrict__ bias, const float* __restrict__ so, float* __restrict__ y)
{
  const float s = so[0], off = so[1];
  const int lane = threadIdx.x & 63;
  const int w    = threadIdx.x >> 6;
  const int m    = lane & 15;
  const int quad = lane >> 4;
  const int rowA = blockIdx.x * 64 + w * 16 + m;
  const float* xp = x + (size_t)rowA * 512 + quad;

  f32x4 acc0 = {0.f,0.f,0.f,0.f}, acc1 = acc0, acc2 = acc0, acc3 = acc0;
  const float c3a = 5.f/3.f, c3b = 2.f/3.f, c6a = 11.f/6.f, c6b = 5.f/6.f, c7a = 13.f/7.f, c7b = 6.f/7.f;

  for (int kt = 0; kt < 128; ++kt) {
    float xv = xp[kt * 4];
    int i = kt * 4 + quad;
    bf16x8 b[4];
    #pragma unroll
    for (int ct = 0; ct < 4; ++ct) {
      const float* cp = coeffs + ((size_t)(ct * 16 + m) * 512 + i) * 8;
      #pragma unroll
      for (int j = 0; j < 8; ++j) b[ct][j] = (__bf16)cp[j];
    }
    float xn = fmaf(xv, s, off);
    float p2 = fmaf(1.5f * xn, xn, -0.5f);
    float p3 = fmaf(c3a * xn, p2, -(c3b * xn));
    float p4 = fmaf(1.75f * xn, p3, -(0.75f * p2));
    float p5 = fmaf(1.8f * xn, p4, -(0.8f * p3));
    float p6 = fmaf(c6a * xn, p5, -(c6b * p4));
    float p7 = fmaf(c7a * xn, p6, -(c7b * p5));
    bf16x8 a;
    a[0] = (__bf16)1.0f; a[1] = (__bf16)xn; a[2] = (__bf16)p2; a[3] = (__bf16)p3;
    a[4] = (__bf16)p4;   a[5] = (__bf16)p5; a[6] = (__bf16)p6; a[7] = (__bf16)p7;
    acc0 = __builtin_amdgcn_mfma_f32_16x16x32_bf16(a, b[0], acc0, 0, 0, 0);
    acc1 = __builtin_amdgcn_mfma_f32_16x16x32_bf16(a, b[1], acc1, 0, 0, 0);
    acc2 = __builtin_amdgcn_mfma_f32_16x16x32_bf16(a, b[2], acc2, 0, 0, 0);
    acc3 = __builtin_amdgcn_mfma_f32_16x16x32_bf16(a, b[3], acc3, 0, 0, 0);
  }
  float b0v = bias[m], b1v = bias[16+m], b2v = bias[32+m], b3v = bias[48+m];
  float* yp = y + ((size_t)(blockIdx.x * 64 + w * 16 + quad * 4)) * 64 + m;
  #pragma unroll
  for (int r = 0; r < 4; ++r) {
    yp[r*64+ 0] = acc0[r] + b0v;
    yp[r*64+16] = acc1[r] + b1v;
    yp[r*64+32] = acc2[r] + b2v;
    yp[r*64+48] = acc3[r] + b3v;
  }
}

extern "C" void kernel_launch(void* const* d_in, const int* in_sizes, int n_in,
                              void* d_out, int out_size, void* d_ws, size_t ws_size,
                              hipStream_t stream)
{
  const float* x      = (const float*)d_in[0];
  const float* coeffs = (const float*)d_in[1];
  const float* bias   = (const float*)d_in[2];
  float* y = (float*)d_out;

  long nx = (long)in_sizes[0];        // 33,554,432
  int  N  = (int)(nx / 512);          // 65536 rows
  int  n4 = (int)(nx / 4);

  float*  so  = (float*)d_ws;
  float*  pmn = (float*)d_ws + 16;
  float*  pmx = pmn + 4096;
  bf16x8* Bws = (bf16x8*)((char*)d_ws + 65536);

  bool pre = ws_size >= (size_t)(65536 + 4096 * 64 * 2 + 4096);
  k_pre<<<NPART, 256, 0, stream>>>((const float4*)x, n4, pmn, pmx, coeffs, Bws, pre ? 1 : 0);
  if (pre) {
    k_main<<<N / 128, 256, 0, stream>>>(x, Bws, bias, pmn, pmx, y);
  } else {
    k_so<<<1, 256, 0, stream>>>(pmn, pmx, NPART, so);
    k_main_simple<<<N / 64, 256, 0, stream>>>(x, coeffs, bias, so, y);
  }
}